// Round 1
// baseline (31875.684 us; speedup 1.0000x reference)
//
#include <hip/hip_runtime.h>

#define B   32
#define L   64
#define DH  1024
#define G4  4096
#define EK  512
#define V   32000
#define NPB 250      // outproj col-blocks (128 cols each)
#define ESTR 264     // LDS staging row stride in floats (16B aligned, padded)

__device__ __forceinline__ float sigm(float x){ return 1.f/(1.f+expf(-x)); }
__device__ __forceinline__ unsigned mono(float f){
  unsigned u = __float_as_uint(f);
  return (u & 0x80000000u) ? ~u : (u | 0x80000000u);
}

// zero h and c (32x1024 each)
__global__ __launch_bounds__(256) void init_kernel(float* h, float* c){
  int i = blockIdx.x*256 + threadIdx.x;
  if (i < B*DH){ h[i]=0.f; c[i]=0.f; }
}

// K-split gates GEMM partials: gp[ch][b][jg] = sum_{k in chunk} X[b][k]*W[k][jg]
// grid (32 colblocks, CH chunks) x 256 thr; thread = 4 cols x 4 rows.
// mode 0 (encoder): phase0 K1=512, X = embed gather. mode 1 (decoder): K1=1024, X = relu(inp).
// Phase1 (k >= K1): X = h_in, W = wh. Chunk size 256 aligns with phase boundaries.
__global__ __launch_bounds__(256) void gates_kernel(
    int mode, int t,
    const int* __restrict__ x, const float* __restrict__ embed,
    const float* __restrict__ src1, int K1,
    const float* __restrict__ wx, const float* __restrict__ wh,
    const float* __restrict__ h_in, float* __restrict__ gp)
{
  __shared__ float es[B][ESTR];
  __shared__ int tok_s[B];
  int tid = threadIdx.x;
  int cb = blockIdx.x, ch = blockIdx.y;
  int ks0 = ch*256;
  const float* W; int krow0;
  if (ks0 < K1){ W = wx; krow0 = ks0; } else { W = wh; krow0 = ks0 - K1; }
  if (mode==0 && ks0 < K1 && tid < B) tok_s[tid] = x[tid*L + t];
  __syncthreads();
  // stage X chunk: es[b][k'] for k' in [0,256); coalesced global, float4
  {
    int bb = tid >> 3;          // 0..31
    int m  = (tid & 7) * 4;     // 0..28
    const float* srow;
    bool do_relu = false;
    if (ks0 < K1){
      if (mode==0) srow = embed + (size_t)tok_s[bb]*EK + ks0;
      else { srow = src1 + (size_t)bb*DH + ks0; do_relu = true; }
    } else {
      srow = h_in + (size_t)bb*DH + (ks0 - K1);
    }
    #pragma unroll
    for (int p=0; p<8; ++p){
      int k = p*32 + m;
      float4 v = *reinterpret_cast<const float4*>(srow + k);
      if (do_relu){
        v.x = fmaxf(v.x,0.f); v.y = fmaxf(v.y,0.f);
        v.z = fmaxf(v.z,0.f); v.w = fmaxf(v.w,0.f);
      }
      *reinterpret_cast<float4*>(&es[bb][k]) = v;
    }
  }
  __syncthreads();
  int cg = tid & 31, rg = tid >> 5;
  int j  = cb*128 + cg*4;
  int r0 = rg*4;
  float4 a0={0,0,0,0}, a1={0,0,0,0}, a2={0,0,0,0}, a3={0,0,0,0};
  const float* wp = W + (size_t)krow0*G4 + j;
  #pragma unroll 16
  for (int k=0; k<256; ++k){
    float4 w = *reinterpret_cast<const float4*>(wp + (size_t)k*G4);
    float x0 = es[r0+0][k], x1 = es[r0+1][k], x2 = es[r0+2][k], x3 = es[r0+3][k];
    a0.x += x0*w.x; a0.y += x0*w.y; a0.z += x0*w.z; a0.w += x0*w.w;
    a1.x += x1*w.x; a1.y += x1*w.y; a1.z += x1*w.z; a1.w += x1*w.w;
    a2.x += x2*w.x; a2.y += x2*w.y; a2.z += x2*w.z; a2.w += x2*w.w;
    a3.x += x3*w.x; a3.y += x3*w.y; a3.z += x3*w.z; a3.w += x3*w.w;
  }
  float* gpr = gp + ((size_t)ch*B)*G4 + j;
  *reinterpret_cast<float4*>(gpr + (size_t)(r0+0)*G4) = a0;
  *reinterpret_cast<float4*>(gpr + (size_t)(r0+1)*G4) = a1;
  *reinterpret_cast<float4*>(gpr + (size_t)(r0+2)*G4) = a2;
  *reinterpret_cast<float4*>(gpr + (size_t)(r0+3)*G4) = a3;
}

// Sum K-chunk partials + bias, apply LSTM cell. grid 128 x 256, one thread per (b,j).
__global__ __launch_bounds__(256) void cell_kernel(
    int CH, int t, const float* __restrict__ gp, const float* __restrict__ bias,
    float* __restrict__ cst, float* __restrict__ h_out, float* __restrict__ enc_outs)
{
  int idx = blockIdx.x*256 + threadIdx.x;   // 0 .. 32*1024
  int b = idx >> 10, jj = idx & 1023;
  float gi = bias[jj], gf = bias[DH+jj], gg = bias[2*DH+jj], go = bias[3*DH+jj];
  const float* g0 = gp + (size_t)b*G4 + jj;
  if (CH == 8){
    #pragma unroll
    for (int ch=0; ch<8; ++ch){
      const float* g = g0 + (size_t)ch*B*G4;
      gi += g[0]; gf += g[DH]; gg += g[2*DH]; go += g[3*DH];
    }
  } else {
    #pragma unroll
    for (int ch=0; ch<6; ++ch){
      const float* g = g0 + (size_t)ch*B*G4;
      gi += g[0]; gf += g[DH]; gg += g[2*DH]; go += g[3*DH];
    }
  }
  float cn = sigm(gf)*cst[idx] + sigm(gi)*tanhf(gg);
  cst[idx] = cn;
  float hv = sigm(go)*tanhf(cn);
  h_out[idx] = hv;
  if (enc_outs) enc_outs[((size_t)b*L + t)*DH + jj] = hv;
}

// Per-step attention; ALSO finishes the previous step's logit reduce (lse + argmax token).
// grid 32 blocks (one per batch row) x 256 thr.
__global__ __launch_bounds__(256) void attn_kernel(
    int t, const float* __restrict__ psum, const unsigned long long* __restrict__ pmax,
    float* __restrict__ lse,
    const float* __restrict__ dec_embed, const float* __restrict__ attn_w,
    const float* __restrict__ attn_b, const float* __restrict__ h_in,
    const float* __restrict__ enc_outs,
    float* __restrict__ e_buf, float* __restrict__ ctxv,
    float* __restrict__ inp, const float* __restrict__ comb_b)
{
  __shared__ float cat_s[2*DH];
  __shared__ float sc_s[16][68];
  __shared__ float aw_s[64];
  __shared__ float rs[256];
  __shared__ unsigned long long rm[256];
  __shared__ int tok_sh;
  int b = blockIdx.x, tid = threadIdx.x;
  // ---- phase A: reduce previous step's outproj partials -> lse[t-1], token ----
  if (t > 0){
    float s = 0.f; unsigned long long mx = 0ull;
    for (int i=tid; i<NPB; i+=256){
      s += psum[b*256 + i];
      unsigned long long v = pmax[b*256 + i];
      if (v > mx) mx = v;
    }
    rs[tid] = s; rm[tid] = mx;
    __syncthreads();
    for (int off=128; off; off>>=1){
      if (tid < off){
        rs[tid] += rs[tid+off];
        if (rm[tid+off] > rm[tid]) rm[tid] = rm[tid+off];
      }
      __syncthreads();
    }
    if (tid==0){
      lse[(t-1)*B + b] = logf(rs[0]);
      tok_sh = (int)(~(unsigned)(rm[0] & 0xffffffffull));
    }
  } else {
    if (tid==0) tok_sh = 127;
  }
  __syncthreads();
  int tok = tok_sh;
  // ---- stage [e; h], emit e_buf, seed inp with comb bias ----
  #pragma unroll
  for (int i=0;i<4;++i){
    int k = i*256 + tid;
    float ev = dec_embed[(size_t)tok*DH + k];
    float hv = h_in[b*DH + k];
    cat_s[k] = ev; cat_s[DH + k] = hv;
    e_buf[b*DH + k] = ev;
    inp[b*DH + k] = comb_b[k];
  }
  __syncthreads();
  // ---- scores: thread = 4 l's (float4 w) x 1/16 of K ----
  {
    int lg = tid & 15, ks = tid >> 4;
    float4 p = {0,0,0,0};
    const float* wp = attn_w + (size_t)(ks*128)*64 + lg*4;
    #pragma unroll 8
    for (int kk=0; kk<128; ++kk){
      float4 w = *reinterpret_cast<const float4*>(wp + (size_t)kk*64);
      float xv = cat_s[ks*128 + kk];
      p.x += xv*w.x; p.y += xv*w.y; p.z += xv*w.z; p.w += xv*w.w;
    }
    *reinterpret_cast<float4*>(&sc_s[ks][lg*4]) = p;
  }
  __syncthreads();
  if (tid < 64){
    float s = attn_b[tid];
    #pragma unroll
    for (int ks=0; ks<16; ++ks) s += sc_s[ks][tid];
    float m = s;
    for (int off=32; off; off>>=1) m = fmaxf(m, __shfl_xor(m, off));
    float e = expf(s - m);
    float sum = e;
    for (int off=32; off; off>>=1) sum += __shfl_xor(sum, off);
    aw_s[tid] = e/sum;
  }
  __syncthreads();
  // ---- ctx = aw @ enc_outs[b] ----
  float c0=0.f,c1=0.f,c2=0.f,c3=0.f;
  const float* eb = enc_outs + (size_t)b*L*DH;
  #pragma unroll 8
  for (int ll=0; ll<64; ++ll){
    float a = aw_s[ll];
    const float* er = eb + (size_t)ll*DH;
    c0 += a*er[tid]; c1 += a*er[256+tid]; c2 += a*er[512+tid]; c3 += a*er[768+tid];
  }
  ctxv[b*DH + tid]       = c0;
  ctxv[b*DH + 256 + tid] = c1;
  ctxv[b*DH + 512 + tid] = c2;
  ctxv[b*DH + 768 + tid] = c3;
}

// Combine GEMM: inp += [e;ctx] @ comb_w (inp pre-seeded with comb_b by attn).
// grid (8 colblocks, 8 K-chunks) x 256; thread 4 cols x 4 rows; atomic accumulate.
__global__ __launch_bounds__(256) void comb_kernel(
    const float* __restrict__ e_buf, const float* __restrict__ ctxv,
    const float* __restrict__ comb_w, float* __restrict__ inp)
{
  __shared__ float es[B][ESTR];
  int tid = threadIdx.x;
  int cb = blockIdx.x, ch = blockIdx.y;
  int ks0 = ch*256;
  const float* src; int off;
  if (ks0 < DH){ src = e_buf; off = ks0; } else { src = ctxv; off = ks0 - DH; }
  {
    int bb = tid >> 3, m = (tid & 7)*4;
    const float* srow = src + (size_t)bb*DH + off;
    #pragma unroll
    for (int p=0; p<8; ++p){
      int k = p*32 + m;
      *reinterpret_cast<float4*>(&es[bb][k]) = *reinterpret_cast<const float4*>(srow + k);
    }
  }
  __syncthreads();
  int cg = tid & 31, rg = tid >> 5;
  int j  = cb*128 + cg*4;
  int r0 = rg*4;
  float4 a0={0,0,0,0}, a1={0,0,0,0}, a2={0,0,0,0}, a3={0,0,0,0};
  const float* wp = comb_w + (size_t)ks0*DH + j;
  #pragma unroll 16
  for (int k=0; k<256; ++k){
    float4 w = *reinterpret_cast<const float4*>(wp + (size_t)k*DH);
    float x0 = es[r0+0][k], x1 = es[r0+1][k], x2 = es[r0+2][k], x3 = es[r0+3][k];
    a0.x += x0*w.x; a0.y += x0*w.y; a0.z += x0*w.z; a0.w += x0*w.w;
    a1.x += x1*w.x; a1.y += x1*w.y; a1.z += x1*w.z; a1.w += x1*w.w;
    a2.x += x2*w.x; a2.y += x2*w.y; a2.z += x2*w.z; a2.w += x2*w.w;
    a3.x += x3*w.x; a3.y += x3*w.y; a3.z += x3*w.z; a3.w += x3*w.w;
  }
  float* p0 = inp + (size_t)(r0+0)*DH + j;
  float* p1 = inp + (size_t)(r0+1)*DH + j;
  float* p2 = inp + (size_t)(r0+2)*DH + j;
  float* p3 = inp + (size_t)(r0+3)*DH + j;
  atomicAdd(p0+0,a0.x); atomicAdd(p0+1,a0.y); atomicAdd(p0+2,a0.z); atomicAdd(p0+3,a0.w);
  atomicAdd(p1+0,a1.x); atomicAdd(p1+1,a1.y); atomicAdd(p1+2,a1.z); atomicAdd(p1+3,a1.w);
  atomicAdd(p2+0,a2.x); atomicAdd(p2+1,a2.y); atomicAdd(p2+2,a2.z); atomicAdd(p2+3,a2.w);
  atomicAdd(p3+0,a3.x); atomicAdd(p3+1,a3.y); atomicAdd(p3+2,a3.z); atomicAdd(p3+3,a3.w);
}

// Output projection: raw logits -> d_out; per-block partial sumexp + packed argmax.
// grid 250 x 256; thread 4 cols x 4 rows; block = 128 cols x 32 rows.
__global__ __launch_bounds__(256) void outproj_kernel(
    int t, const float* __restrict__ hsrc, const float* __restrict__ out_w,
    const float* __restrict__ out_b, float* __restrict__ out,
    float* __restrict__ psum, unsigned long long* __restrict__ pmax)
{
  __shared__ float hs[256][36];
  __shared__ float red_s[B][33];
  __shared__ unsigned long long pk_s[B][33];
  int tid = threadIdx.x;
  int cg = tid & 31, rg = tid >> 5;
  int j  = blockIdx.x*128 + cg*4;
  int r0 = rg*4;
  float4 a0={0,0,0,0}, a1={0,0,0,0}, a2={0,0,0,0}, a3={0,0,0,0};
  for (int kb=0; kb<DH; kb+=256){
    {
      int bb = tid >> 3, m = (tid & 7)*4;
      const float* hrow = hsrc + (size_t)bb*DH + kb;
      #pragma unroll
      for (int p=0; p<8; ++p){
        int k = p*32 + m;
        float4 v = *reinterpret_cast<const float4*>(hrow + k);
        hs[k+0][bb]=v.x; hs[k+1][bb]=v.y; hs[k+2][bb]=v.z; hs[k+3][bb]=v.w;
      }
    }
    __syncthreads();
    const float* wp = out_w + (size_t)kb*V + j;
    #pragma unroll 16
    for (int k=0; k<256; ++k){
      float4 w  = *reinterpret_cast<const float4*>(wp + (size_t)k*V);
      float4 hv = *reinterpret_cast<const float4*>(&hs[k][r0]);
      a0.x += hv.x*w.x; a0.y += hv.x*w.y; a0.z += hv.x*w.z; a0.w += hv.x*w.w;
      a1.x += hv.y*w.x; a1.y += hv.y*w.y; a1.z += hv.y*w.z; a1.w += hv.y*w.w;
      a2.x += hv.z*w.x; a2.y += hv.z*w.y; a2.z += hv.z*w.z; a2.w += hv.z*w.w;
      a3.x += hv.w*w.x; a3.y += hv.w*w.y; a3.z += hv.w*w.z; a3.w += hv.w*w.w;
    }
    __syncthreads();
  }
  float4 bb4 = *reinterpret_cast<const float4*>(out_b + j);
  float4 lg[4];
  lg[0].x = a0.x+bb4.x; lg[0].y = a0.y+bb4.y; lg[0].z = a0.z+bb4.z; lg[0].w = a0.w+bb4.w;
  lg[1].x = a1.x+bb4.x; lg[1].y = a1.y+bb4.y; lg[1].z = a1.z+bb4.z; lg[1].w = a1.w+bb4.w;
  lg[2].x = a2.x+bb4.x; lg[2].y = a2.y+bb4.y; lg[2].z = a2.z+bb4.z; lg[2].w = a2.w+bb4.w;
  lg[3].x = a3.x+bb4.x; lg[3].y = a3.y+bb4.y; lg[3].z = a3.z+bb4.z; lg[3].w = a3.w+bb4.w;
  #pragma unroll
  for (int r=0; r<4; ++r){
    int b = r0 + r;
    *reinterpret_cast<float4*>(&out[((size_t)b*L + t)*V + j]) = lg[r];
    float se = expf(lg[r].x) + expf(lg[r].y) + expf(lg[r].z) + expf(lg[r].w);
    unsigned long long m0 = ((unsigned long long)mono(lg[r].x)<<32) | (~(unsigned)(j+0));
    unsigned long long m1 = ((unsigned long long)mono(lg[r].y)<<32) | (~(unsigned)(j+1));
    unsigned long long m2 = ((unsigned long long)mono(lg[r].z)<<32) | (~(unsigned)(j+2));
    unsigned long long m3 = ((unsigned long long)mono(lg[r].w)<<32) | (~(unsigned)(j+3));
    if (m1 > m0) m0 = m1;
    if (m3 > m2) m2 = m3;
    if (m2 > m0) m0 = m2;
    red_s[b][cg] = se;
    pk_s[b][cg]  = m0;
  }
  __syncthreads();
  if (tid < B){
    float s = 0.f; unsigned long long mx = 0ull;
    #pragma unroll 8
    for (int cc=0; cc<32; ++cc){
      s += red_s[tid][cc];
      unsigned long long v = pk_s[tid][cc];
      if (v > mx) mx = v;
    }
    psum[tid*256 + blockIdx.x] = s;
    pmax[tid*256 + blockIdx.x] = mx;
  }
}

// lse for the last step (no following attn to fold it into). grid 32 x 256.
__global__ __launch_bounds__(256) void lastlse_kernel(
    const float* __restrict__ psum, float* __restrict__ lse)
{
  __shared__ float rs[256];
  int b = blockIdx.x, tid = threadIdx.x;
  float s = 0.f;
  for (int i=tid; i<NPB; i+=256) s += psum[b*256 + i];
  rs[tid] = s;
  __syncthreads();
  for (int off=128; off; off>>=1){
    if (tid < off) rs[tid] += rs[tid+off];
    __syncthreads();
  }
  if (tid==0) lse[(L-1)*B + b] = logf(rs[0]);
}

// Deferred log-softmax normalization over the whole output, one parallel pass.
// grid (125, B, L) x 256.
__global__ __launch_bounds__(256) void norm_kernel(
    float* __restrict__ out, const float* __restrict__ lse)
{
  int v = blockIdx.x*256 + threadIdx.x;
  int b = blockIdx.y, t = blockIdx.z;
  out[((size_t)b*L + t)*V + v] -= lse[t*B + b];
}

extern "C" void kernel_launch(void* const* d_in, const int* in_sizes, int n_in,
                              void* d_out, int out_size, void* d_ws, size_t ws_size,
                              hipStream_t stream)
{
  const int*   x         = (const int*)  d_in[0];
  const float* enc_embed = (const float*)d_in[1];
  const float* enc_wx    = (const float*)d_in[2];
  const float* enc_wh    = (const float*)d_in[3];
  const float* enc_b     = (const float*)d_in[4];
  const float* dec_embed = (const float*)d_in[5];
  const float* attn_w    = (const float*)d_in[6];
  const float* attn_b    = (const float*)d_in[7];
  const float* comb_w    = (const float*)d_in[8];
  const float* comb_b    = (const float*)d_in[9];
  const float* dec_wx    = (const float*)d_in[10];
  const float* dec_wh    = (const float*)d_in[11];
  const float* dec_b     = (const float*)d_in[12];
  const float* out_w     = (const float*)d_in[13];
  const float* out_b     = (const float*)d_in[14];
  float* out = (float*)d_out;

  float* enc_outs = (float*)d_ws;                  // 32*64*1024       = 2,097,152 f
  float* h0    = enc_outs + (size_t)B*L*DH;        // 32*1024
  float* h1    = h0 + B*DH;
  float* c     = h1 + B*DH;
  float* e_buf = c  + B*DH;
  float* ctxv  = e_buf + B*DH;
  float* inp   = ctxv + B*DH;
  float* gpart = inp + B*DH;                       // 8*32*4096        = 1,048,576 f
  float* psum  = gpart + (size_t)8*B*G4;           // 32*256
  float* lse   = psum + B*256;                     // 64*32
  unsigned long long* pmax = (unsigned long long*)(lse + L*B); // 32*256 ull

  // ---- encoder ----
  init_kernel<<<128,256,0,stream>>>(h0, c);
  for (int t=0; t<L; ++t){
    const float* hi = (t&1) ? h1 : h0;
    float*       ho = (t&1) ? h0 : h1;
    gates_kernel<<<dim3(32,6),256,0,stream>>>(0, t, x, enc_embed, nullptr, EK,
        enc_wx, enc_wh, hi, gpart);
    cell_kernel<<<128,256,0,stream>>>(6, t, gpart, enc_b, c, ho, enc_outs);
  }
  // ---- decoder ----
  init_kernel<<<128,256,0,stream>>>(h0, c);
  for (int t=0; t<L; ++t){
    const float* hi = (t&1) ? h1 : h0;
    float*       ho = (t&1) ? h0 : h1;
    attn_kernel<<<B,256,0,stream>>>(t, psum, pmax, lse, dec_embed, attn_w, attn_b,
        hi, enc_outs, e_buf, ctxv, inp, comb_b);
    comb_kernel<<<dim3(8,8),256,0,stream>>>(e_buf, ctxv, comb_w, inp);
    gates_kernel<<<dim3(32,8),256,0,stream>>>(1, t, nullptr, nullptr, inp, DH,
        dec_wx, dec_wh, hi, gpart);
    cell_kernel<<<128,256,0,stream>>>(8, t, gpart, dec_b, c, ho, nullptr);
    outproj_kernel<<<NPB,256,0,stream>>>(t, ho, out_w, out_b, out, psum, pmax);
  }
  lastlse_kernel<<<B,256,0,stream>>>(psum, lse);
  norm_kernel<<<dim3(125,B,L),256,0,stream>>>(out, lse);
}